// Round 8
// baseline (164.569 us; speedup 1.0000x reference)
//
#include <hip/hip_runtime.h>

typedef unsigned short u16;
typedef unsigned int   u32;
typedef unsigned long long u64;

typedef __bf16 bf16x8 __attribute__((ext_vector_type(8)));
typedef float  f32x4  __attribute__((ext_vector_type(4)));

#define MFMA_BF16(a,b,c) __builtin_amdgcn_mfma_f32_16x16x32_bf16((a),(b),(c),0,0,0)

__device__ __forceinline__ float bf2f(u16 u) {
    return __uint_as_float(((u32)u) << 16);
}
__device__ __forceinline__ u16 f2bf(float x) {
    u32 u = __float_as_uint(x);
    u += 0x7fffu + ((u >> 16) & 1u);   // RNE
    return (u16)(u >> 16);
}
__device__ __forceinline__ float ldany(const void* p, size_t i, int f32) {
    return f32 ? ((const float*)p)[i] : bf2f(((const u16*)p)[i]);
}
// fp32-vs-bf16 detect from first 64 words of h; identical in every wave.
__device__ __forceinline__ int detect_f32(const u32* hw) {
    u32 w = hw[threadIdx.x & 63];
    int e = (w >> 23) & 0xFF;
    u64 m = __ballot(e >= 64 && e <= 190);
    return __popcll(m) >= 32 ? 1 : 0;
}

// ---------------- K0: 256 blocks — WT col + Wa1/Wa2 row-reduce -----------
__global__ __launch_bounds__(256) void k0(const void* __restrict__ w, const void* __restrict__ a,
                                          u16* __restrict__ wt, float* __restrict__ wa1,
                                          float* __restrict__ wa2, const u32* __restrict__ hw) {
    int f32 = detect_f32(hw);
    int k = blockIdx.x, o = threadIdx.x;
    float wv = ldany(w, (size_t)k * 256 + o, f32);
    wt[o * 256 + k] = f2bf(wv);
    float p1 = wv * ldany(a, o, f32);
    float p2 = wv * ldany(a, 256 + o, f32);
    for (int d = 32; d; d >>= 1) { p1 += __shfl_down(p1, d); p2 += __shfl_down(p2, d); }
    __shared__ float s1[4], s2[4];
    int wid = o >> 6, lane = o & 63;
    if (lane == 0) { s1[wid] = p1; s2[wid] = p2; }
    __syncthreads();
    if (o == 0) { wa1[k] = s1[0] + s1[1] + s1[2] + s1[3]; wa2[k] = s2[0] + s2[1] + s2[2] + s2[3]; }
}

// ---------------- K1: exact fp32 s_i/s_j + mask bitset (round-6 form) ----
__global__ __launch_bounds__(256) void k1(const void* __restrict__ h,
                                          const float* __restrict__ wa1, const float* __restrict__ wa2,
                                          const int* __restrict__ adj,
                                          float* __restrict__ si, float* __restrict__ sj,
                                          u64* __restrict__ mb64) {
    int f32 = detect_f32((const u32*)h);
    int t = threadIdx.x;
    int wv = t >> 6, lane = t & 63;
    int row = blockIdx.x * 4 + wv;
    size_t base = (size_t)row * 256;
    float a1 = 0.f, a2 = 0.f;
    for (int p = 0; p < 4; p++) {
        int f = lane + p * 64;
        float hv = ldany(h, base + f, f32);
        a1 += hv * wa1[f];
        a2 += hv * wa2[f];
    }
    for (int d = 32; d; d >>= 1) { a1 += __shfl_down(a1, d); a2 += __shfl_down(a2, d); }
    if (lane == 0) { si[row] = a1; sj[row] = a2; }
    #pragma unroll
    for (int q = 0; q < 4; q++) {
        int idx = blockIdx.x * 16 + wv * 4 + q;        // 65536 words
        int mrow = idx >> 5, c = idx & 31;
        int j = c * 64 + lane;
        bool bit = (adj[(size_t)mrow * 2048 + j] > 0) || (j == mrow);
        u64 m = __ballot(bit);
        if (lane == 0) mb64[(size_t)mrow * 32 + c] = m;
    }
}

// ---------------- K2: Whb_t[b][f][n] = bf16((h@W)^T), linear layout ------
// 256 blocks, 64-row tiles. LDS-transpose epilogue -> contiguous 16B stores.
struct __align__(16) K2LDS {
    u16 At[64 * 68];
    union { u16 Bt[256 * 68]; u16 Ct[256 * 68]; };
};
__global__ __launch_bounds__(256) void k2(const void* __restrict__ h, const u16* __restrict__ wt,
                                          u16* __restrict__ whbt) {
    __shared__ K2LDS L;
    int f32 = detect_f32((const u32*)h);
    int m0 = blockIdx.x * 64;
    int b  = m0 >> 11;
    int n0 = m0 & 2047;
    int t = threadIdx.x;
    int wid = t >> 6, lane = t & 63, ln = lane & 15, qd = lane >> 4;

    f32x4 acc[4][4];
    for (int mi = 0; mi < 4; mi++)
        for (int ni = 0; ni < 4; ni++)
            acc[mi][ni] = (f32x4){0.f, 0.f, 0.f, 0.f};

    for (int c = 0; c < 4; c++) {
        int k0c = c * 64;
        for (int p = 0; p < 2; p++) {
            int r = (t >> 3) + p * 32, s = t & 7;
            if (f32) {
                const float* src = (const float*)h + (size_t)(m0 + r) * 256 + k0c + s * 8;
                f32x4 x0 = *(const f32x4*)src;
                f32x4 x1 = *(const f32x4*)(src + 4);
                u16 v[8];
                for (int q = 0; q < 4; q++) { v[q] = f2bf(x0[q]); v[4 + q] = f2bf(x1[q]); }
                *(uint4*)&L.At[r * 68 + s * 8] = *(uint4*)v;
            } else {
                *(uint4*)&L.At[r * 68 + s * 8] =
                    *(const uint4*)((const u16*)h + (size_t)(m0 + r) * 256 + k0c + s * 8);
            }
        }
        for (int p = 0; p < 8; p++) {
            int f = (t >> 3) + p * 32, s = t & 7;
            *(uint4*)&L.Bt[f * 68 + s * 8] =
                *(const uint4*)(wt + (size_t)f * 256 + k0c + s * 8);
        }
        __syncthreads();
        for (int ks = 0; ks < 2; ks++) {
            bf16x8 af[4], bfr[4];
            for (int mi = 0; mi < 4; mi++)
                af[mi] = *(const bf16x8*)&L.At[(mi * 16 + ln) * 68 + ks * 32 + qd * 8];
            for (int ni = 0; ni < 4; ni++)
                bfr[ni] = *(const bf16x8*)&L.Bt[(wid * 64 + ni * 16 + ln) * 68 + ks * 32 + qd * 8];
            for (int mi = 0; mi < 4; mi++)
                for (int ni = 0; ni < 4; ni++)
                    acc[mi][ni] = MFMA_BF16(af[mi], bfr[ni], acc[mi][ni]);
        }
        __syncthreads();
    }
    // transpose via LDS: Ct[f][n-local], then contiguous linear stores
    for (int mi = 0; mi < 4; mi++) {
        for (int ni = 0; ni < 4; ni++) {
            int f = wid * 64 + ni * 16 + ln;
            int n = mi * 16 + qd * 4;
            u16 v[4];
            for (int r = 0; r < 4; r++) v[r] = f2bf(acc[mi][ni][r]);
            *(uint2*)&L.Ct[f * 68 + n] = *(uint2*)v;
        }
    }
    __syncthreads();
    {
        int fr = t;
        size_t base = (size_t)b * 524288 + (size_t)fr * 2048 + n0;
        #pragma unroll
        for (int s = 0; s < 8; s++) {
            uint4 v = *(uint4*)&L.Ct[fr * 68 + s * 8];
            *(uint4*)(whbt + base + s * 8) = v;
        }
    }
}

// ---------------- K3n: per-batch shift + factored-exp tables -------------
__global__ __launch_bounds__(512) void k3n(const float* __restrict__ sig, const float* __restrict__ sjg,
                                           float* __restrict__ u1g, float* __restrict__ u2g,
                                           u32* __restrict__ vpackg, u16* __restrict__ sjbfg) {
    int b = blockIdx.x;           // 8 blocks, one per batch
    int t = threadIdx.x;          // 512
    const float* sjb = sjg + (size_t)b * 2048;
    float mx = -3.4e38f;
    #pragma unroll
    for (int p = 0; p < 4; p++) mx = fmaxf(mx, sjb[t + p * 512]);
    for (int d = 32; d; d >>= 1) mx = fmaxf(mx, __shfl_xor(mx, d));
    __shared__ float wmax[8];
    int wid = t >> 6, lane = t & 63;
    if (lane == 0) wmax[wid] = mx;
    __syncthreads();
    float Mb = fmaxf(fmaxf(fmaxf(wmax[0], wmax[1]), fmaxf(wmax[2], wmax[3])),
                     fmaxf(fmaxf(wmax[4], wmax[5]), fmaxf(wmax[6], wmax[7])));
    #pragma unroll
    for (int p = 0; p < 4; p++) {
        int j = t + p * 512;
        float sjv = sjb[j];
        float vj  = __expf(sjv - Mb);            // <= 1
        float v2j = __expf(0.2f * (sjv - Mb));   // <= 1
        vpackg[b * 2048 + j] = (u32)f2bf(vj) | ((u32)f2bf(v2j) << 16);
        sjbfg[b * 2048 + j]  = f2bf(sjv);
        float siv = sig[b * 2048 + j];
        float x = siv + Mb;
        float K = fmaxf(x, 0.2f * x);            // lrelu(s_i + Mb)
        u1g[b * 2048 + j] = __expf(x - K);       // <= 1
        u2g[b * 2048 + j] = __expf(0.2f * x - K);// <= 1
    }
}

// ---------------- K4: reg-prefetched B + P-gen + P@Whb + inline-l + ELU --
// 512 blocks x 256 thr (2/CU): b = bid&7 (XCD-resident Whb[b]),
// i-tile = bid>>3 (32 rows). B-frags loaded GLOBAL->VGPR (no LDS staging).
struct __align__(16) K4LDS {
    u32   vpack[2048];                 // 8192 B
    u16   sjb[2048];                   // 4096 B
    u64   mw[32 * 33];                 // 8448 B
    float u1[32], u2[32], nsi[32], inv[32];
    float lred[256];
    u16   Pt[2][2048];                 // 2 x 4096 B, [octet][row][8]
};
__global__ __launch_bounds__(256, 2) void k4(const float* __restrict__ sig,
                                             const float* __restrict__ u1g, const float* __restrict__ u2g,
                                             const u32* __restrict__ vpackg, const u16* __restrict__ sjbfg,
                                             const u64* __restrict__ mb64, const u16* __restrict__ whbt,
                                             void* __restrict__ out, const void* __restrict__ hdet) {
    __shared__ K4LDS L;
    int f32 = detect_f32((const u32*)hdet);
    int b  = blockIdx.x & 7;
    int i0 = (blockIdx.x >> 3) * 32;
    int t = threadIdx.x;
    int wid = t >> 6, lane = t & 63, ln = lane & 15, qd = lane >> 4;
    const u16* wb = whbt + (size_t)b * 524288 + (size_t)wid * 64 * 2048;
    float lacc = 0.f;

    // B-fragment loads for chunk cc into br[bb][ni*2+ks]
    bf16x8 br[2][8];
    #define LOAD_B(cc, bb) do {                                             \
        int j0_ = (cc) * 64;                                                \
        _Pragma("unroll")                                                   \
        for (int ni = 0; ni < 4; ni++)                                      \
            _Pragma("unroll")                                               \
            for (int ks = 0; ks < 2; ks++)                                  \
                br[bb][ni * 2 + ks] = *(const bf16x8*)(wb +                 \
                    (size_t)(ni * 16 + ln) * 2048 + j0_ + ks * 32 + qd * 8);\
    } while (0)

    // Factored P-gen: thread -> row t&31, j-octet t>>5; accumulates lacc.
    #define PGEN(cc, bb) do {                                               \
        int r_ = t & 31, o_ = t >> 5;                                       \
        int jb_ = (cc) * 64 + o_ * 8;                                       \
        uint4 pkA_ = *(const uint4*)&L.vpack[jb_];                          \
        uint4 pkB_ = *(const uint4*)&L.vpack[jb_ + 4];                      \
        uint4 sj4_ = *(const uint4*)&L.sjb[jb_];                            \
        u32 mb_ = (u32)(L.mw[r_ * 33 + (cc)] >> (o_ * 8)) & 0xffu;          \
        float u1_ = L.u1[r_], u2_ = L.u2[r_], nsi_ = L.nsi[r_];             \
        u32 pr_[4];                                                         \
        _Pragma("unroll")                                                   \
        for (int pk = 0; pk < 4; pk++) {                                    \
            u32 vw0_ = (pk == 0) ? pkA_.x : (pk == 1) ? pkA_.z              \
                     : (pk == 2) ? pkB_.x : pkB_.z;                         \
            u32 vw1_ = (pk == 0) ? pkA_.y : (pk == 1) ? pkA_.w              \
                     : (pk == 2) ? pkB_.y : pkB_.w;                         \
            u32 sw_ = (pk == 0) ? sj4_.x : (pk == 1) ? sj4_.y               \
                     : (pk == 2) ? sj4_.z : sj4_.w;                         \
            float sj0_ = __uint_as_float(sw_ << 16);                        \
            float sj1_ = __uint_as_float(sw_ & 0xffff0000u);                \
            float p0_, p1_;                                                 \
            {                                                               \
                bool pos = sj0_ > nsi_;                                     \
                float vv = __uint_as_float(pos ? (vw0_ << 16)               \
                                               : ((vw0_ >> 16) << 16));     \
                p0_ = (pos ? u1_ : u2_) * vv;                               \
                p0_ = ((mb_ >> (2 * pk)) & 1u) ? p0_ : 0.f;                 \
            }                                                               \
            {                                                               \
                bool pos = sj1_ > nsi_;                                     \
                float vv = __uint_as_float(pos ? (vw1_ << 16)               \
                                               : ((vw1_ >> 16) << 16));     \
                p1_ = (pos ? u1_ : u2_) * vv;                               \
                p1_ = ((mb_ >> (2 * pk + 1)) & 1u) ? p1_ : 0.f;             \
            }                                                               \
            lacc += p0_ + p1_;                                              \
            pr_[pk] = __builtin_amdgcn_perm(__float_as_uint(p1_),           \
                                            __float_as_uint(p0_),           \
                                            0x07060302u);                   \
        }                                                                   \
        *(uint4*)&L.Pt[bb][t * 8] = *(uint4*)pr_;                           \
    } while (0)

    LOAD_B(0, 0);
    // stage tables
    for (int p = 0; p < 8; p++) { int idx = t + p * 256; L.vpack[idx] = vpackg[b * 2048 + idx]; }
    for (int p = 0; p < 4; p++) { int idx = t + p * 256;
        ((u32*)L.sjb)[idx] = ((const u32*)(sjbfg + (size_t)b * 2048))[idx]; }
    for (int p = 0; p < 4; p++) {
        int idx = t + p * 256;                          // 1024 u64 words
        int r = idx >> 5, c = idx & 31;
        L.mw[r * 33 + c] = mb64[(size_t)(i0 + r) * 32 + c];
    }
    if (t < 32) {
        int row = b * 2048 + i0 + t;
        L.u1[t] = u1g[row]; L.u2[t] = u2g[row]; L.nsi[t] = -sig[row];
    }
    __syncthreads();
    PGEN(0, 0);

    f32x4 acc[2][4];
    for (int mi = 0; mi < 2; mi++)
        for (int ni = 0; ni < 4; ni++)
            acc[mi][ni] = (f32x4){0.f, 0.f, 0.f, 0.f};

    // one barrier per K-chunk; B(c+1) in regs + PGEN(c+1) overlap MFMA(c)
    #define STEP(c, cur, nxt) do {                                          \
        __syncthreads();                                                    \
        if ((c) < 31) { LOAD_B((c) + 1, nxt); PGEN((c) + 1, nxt); }         \
        _Pragma("unroll")                                                   \
        for (int ks = 0; ks < 2; ks++) {                                    \
            bf16x8 af[2];                                                   \
            _Pragma("unroll")                                               \
            for (int mi = 0; mi < 2; mi++)                                  \
                af[mi] = *(const bf16x8*)&L.Pt[cur][((ks * 4 + qd) * 32 +   \
                                                     mi * 16 + ln) * 8];    \
            _Pragma("unroll")                                               \
            for (int mi = 0; mi < 2; mi++)                                  \
                _Pragma("unroll")                                           \
                for (int ni = 0; ni < 4; ni++)                              \
                    acc[mi][ni] = MFMA_BF16(af[mi], br[cur][ni * 2 + ks],   \
                                            acc[mi][ni]);                   \
        }                                                                   \
    } while (0)

    for (int cc = 0; cc < 16; cc++) {
        STEP(2 * cc,     0, 1);
        STEP(2 * cc + 1, 1, 0);
    }

    // reduce row sums l_i: 8 partials per row (t = o*32 + r)
    __syncthreads();
    L.lred[t] = lacc;
    __syncthreads();
    if (t < 32) {
        float s = 0.f;
        #pragma unroll
        for (int q = 0; q < 8; q++) s += L.lred[q * 32 + t];
        L.inv[t] = 1.0f / s;
    }
    __syncthreads();

    // epilogue: h_prime = acc * inv_l, ELU, store
    for (int mi = 0; mi < 2; mi++) {
        for (int ni = 0; ni < 4; ni++) {
            int fg = wid * 64 + ni * 16 + ln;
            for (int reg = 0; reg < 4; reg++) {
                int rl = mi * 16 + qd * 4 + reg;
                float hp = acc[mi][ni][reg] * L.inv[rl];
                float y = hp > 0.f ? hp : (__expf(hp) - 1.f);
                size_t idx = (size_t)(b * 2048 + i0 + rl) * 256 + fg;
                if (f32) ((float*)out)[idx] = y;
                else     ((u16*)out)[idx]   = f2bf(y);
            }
        }
    }
    #undef LOAD_B
    #undef PGEN
    #undef STEP
}

// ---------------- launch --------------------------------------------------
extern "C" void kernel_launch(void* const* d_in, const int* in_sizes, int n_in,
                              void* d_out, int out_size, void* d_ws, size_t ws_size,
                              hipStream_t stream) {
    const void* h   = d_in[0];              // (8,2048,256) fp32 (detected) or bf16
    const int*  adj = (const int*)d_in[1];  // int32 (2048,2048)
    const void* W   = d_in[2];              // (256,256)
    const void* a   = d_in[3];              // (512,1)

    char* ws = (char*)d_ws;
    u16*   WT    = (u16*)  (ws + 0);        // 131072
    float* si    = (float*)(ws + 131072);   // 65536
    float* sj    = (float*)(ws + 196608);   // 65536
    float* u1    = (float*)(ws + 262144);   // 65536
    float* u2    = (float*)(ws + 327680);   // 65536
    u32*   vpack = (u32*)  (ws + 458752);   // 65536
    u16*   sjbf  = (u16*)  (ws + 524288);   // 32768
    u64*   mb64  = (u64*)  (ws + 557056);   // 524288
    u16*   whbt  = (u16*)  (ws + 1081344);  // 8388608 (end 9469952)
    float* Wa1   = (float*)(ws + 9469952);  // 1024
    float* Wa2   = (float*)(ws + 9470976);  // 1024

    k0 <<<dim3(256),  dim3(256), 0, stream>>>(W, a, WT, Wa1, Wa2, (const u32*)h);
    k1 <<<dim3(4096), dim3(256), 0, stream>>>(h, Wa1, Wa2, adj, si, sj, mb64);
    k2 <<<dim3(256),  dim3(256), 0, stream>>>(h, WT, whbt);
    k3n<<<dim3(8),    dim3(512), 0, stream>>>(si, sj, u1, u2, vpack, sjbf);
    k4 <<<dim3(512),  dim3(256), 0, stream>>>(si, u1, u2, vpack, sjbf, mb64, whbt, d_out, h);
}

// Round 9
// 139.484 us; speedup vs baseline: 1.1798x; 1.1798x over previous
//
#include <hip/hip_runtime.h>

typedef unsigned short u16;
typedef unsigned int   u32;
typedef unsigned long long u64;

typedef __bf16 bf16x8 __attribute__((ext_vector_type(8)));
typedef float  f32x4  __attribute__((ext_vector_type(4)));

#define MFMA_BF16(a,b,c) __builtin_amdgcn_mfma_f32_16x16x32_bf16((a),(b),(c),0,0,0)

__device__ __forceinline__ float bf2f(u16 u) {
    return __uint_as_float(((u32)u) << 16);
}
__device__ __forceinline__ u16 f2bf(float x) {
    u32 u = __float_as_uint(x);
    u += 0x7fffu + ((u >> 16) & 1u);   // RNE
    return (u16)(u >> 16);
}
__device__ __forceinline__ float ldany(const void* p, size_t i, int f32) {
    return f32 ? ((const float*)p)[i] : bf2f(((const u16*)p)[i]);
}
// fp32-vs-bf16 detect from first 64 words of h; identical in every wave.
__device__ __forceinline__ int detect_f32(const u32* hw) {
    u32 w = hw[threadIdx.x & 63];
    int e = (w >> 23) & 0xFF;
    u64 m = __ballot(e >= 64 && e <= 190);
    return __popcll(m) >= 32 ? 1 : 0;
}

// ---------------- K0: 256 blocks — WT col + Wa1/Wa2 row-reduce -----------
__global__ __launch_bounds__(256) void k0(const void* __restrict__ w, const void* __restrict__ a,
                                          u16* __restrict__ wt, float* __restrict__ wa1,
                                          float* __restrict__ wa2, const u32* __restrict__ hw) {
    int f32 = detect_f32(hw);
    int k = blockIdx.x, o = threadIdx.x;
    float wv = ldany(w, (size_t)k * 256 + o, f32);
    wt[o * 256 + k] = f2bf(wv);
    float p1 = wv * ldany(a, o, f32);
    float p2 = wv * ldany(a, 256 + o, f32);
    for (int d = 32; d; d >>= 1) { p1 += __shfl_down(p1, d); p2 += __shfl_down(p2, d); }
    __shared__ float s1[4], s2[4];
    int wid = o >> 6, lane = o & 63;
    if (lane == 0) { s1[wid] = p1; s2[wid] = p2; }
    __syncthreads();
    if (o == 0) { wa1[k] = s1[0] + s1[1] + s1[2] + s1[3]; wa2[k] = s2[0] + s2[1] + s2[2] + s2[3]; }
}

// ---------------- K1m: mask bitset only ----------------------------------
__global__ __launch_bounds__(256) void k1m(const int* __restrict__ adj, u64* __restrict__ mb64) {
    int t = threadIdx.x;
    int wv = t >> 6, lane = t & 63;
    #pragma unroll
    for (int q = 0; q < 4; q++) {
        int idx = blockIdx.x * 16 + wv * 4 + q;        // 65536 words
        int mrow = idx >> 5, c = idx & 31;
        int j = c * 64 + lane;
        bool bit = (adj[(size_t)mrow * 2048 + j] > 0) || (j == mrow);
        u64 m = __ballot(bit);
        if (lane == 0) mb64[(size_t)mrow * 32 + c] = m;
    }
}

// ---------------- K2: Whb_t = bf16((h@W)^T) + EXACT fp32 s_i/s_j ---------
// s_i = h·(W@a1) accumulated from the fp32 h values during staging (the
// round-7 bug dotted Wh with W@a1; here it is h·(W@a1) — k1's exact math).
struct __align__(16) K2LDS {
    u16 At[64 * 68];
    union { u16 Bt[256 * 68]; u16 Ct[256 * 68]; };
    float wa1s[256], wa2s[256];
    float s1[64], s2[64];
};
__global__ __launch_bounds__(256) void k2(const void* __restrict__ h, const u16* __restrict__ wt,
                                          const float* __restrict__ wa1, const float* __restrict__ wa2,
                                          u16* __restrict__ whbt,
                                          float* __restrict__ sig, float* __restrict__ sjg) {
    __shared__ K2LDS L;
    int f32 = detect_f32((const u32*)h);
    int m0 = blockIdx.x * 64;
    int b  = m0 >> 11;
    int n0 = m0 & 2047;
    int t = threadIdx.x;
    int wid = t >> 6, lane = t & 63, ln = lane & 15, qd = lane >> 4;

    L.wa1s[t] = wa1[t]; L.wa2s[t] = wa2[t];
    if (t < 64) { L.s1[t] = 0.f; L.s2[t] = 0.f; }
    __syncthreads();

    float a1lo = 0.f, a2lo = 0.f, a1hi = 0.f, a2hi = 0.f;

    f32x4 acc[4][4];
    for (int mi = 0; mi < 4; mi++)
        for (int ni = 0; ni < 4; ni++)
            acc[mi][ni] = (f32x4){0.f, 0.f, 0.f, 0.f};

    for (int c = 0; c < 4; c++) {
        int k0c = c * 64;
        for (int p = 0; p < 2; p++) {
            int r = (t >> 3) + p * 32, s = t & 7;
            float xv[8]; u16 uv[8];
            if (f32) {
                const float* src = (const float*)h + (size_t)(m0 + r) * 256 + k0c + s * 8;
                f32x4 x0 = *(const f32x4*)src;
                f32x4 x1 = *(const f32x4*)(src + 4);
                #pragma unroll
                for (int q = 0; q < 4; q++) { xv[q] = x0[q]; xv[4 + q] = x1[q]; }
                #pragma unroll
                for (int q = 0; q < 8; q++) uv[q] = f2bf(xv[q]);
            } else {
                const u16* src = (const u16*)h + (size_t)(m0 + r) * 256 + k0c + s * 8;
                *(uint4*)uv = *(const uint4*)src;
                #pragma unroll
                for (int q = 0; q < 8; q++) xv[q] = bf2f(uv[q]);
            }
            *(uint4*)&L.At[r * 68 + s * 8] = *(uint4*)uv;
            float pa = 0.f, pb = 0.f;
            #pragma unroll
            for (int q = 0; q < 8; q++) {
                pa += xv[q] * L.wa1s[k0c + s * 8 + q];
                pb += xv[q] * L.wa2s[k0c + s * 8 + q];
            }
            if (p == 0) { a1lo += pa; a2lo += pb; } else { a1hi += pa; a2hi += pb; }
        }
        for (int p = 0; p < 8; p++) {
            int f = (t >> 3) + p * 32, s = t & 7;
            *(uint4*)&L.Bt[f * 68 + s * 8] =
                *(const uint4*)(wt + (size_t)f * 256 + k0c + s * 8);
        }
        __syncthreads();
        for (int ks = 0; ks < 2; ks++) {
            bf16x8 af[4], bfr[4];
            for (int mi = 0; mi < 4; mi++)
                af[mi] = *(const bf16x8*)&L.At[(mi * 16 + ln) * 68 + ks * 32 + qd * 8];
            for (int ni = 0; ni < 4; ni++)
                bfr[ni] = *(const bf16x8*)&L.Bt[(wid * 64 + ni * 16 + ln) * 68 + ks * 32 + qd * 8];
            for (int mi = 0; mi < 4; mi++)
                for (int ni = 0; ni < 4; ni++)
                    acc[mi][ni] = MFMA_BF16(af[mi], bfr[ni], acc[mi][ni]);
        }
        __syncthreads();
    }

    // s partials: 8 threads per row
    atomicAdd(&L.s1[t >> 3], a1lo);        atomicAdd(&L.s2[t >> 3], a2lo);
    atomicAdd(&L.s1[(t >> 3) + 32], a1hi); atomicAdd(&L.s2[(t >> 3) + 32], a2hi);

    // transpose via LDS: Ct[f][n-local], then contiguous linear stores
    for (int mi = 0; mi < 4; mi++) {
        for (int ni = 0; ni < 4; ni++) {
            int f = wid * 64 + ni * 16 + ln;
            int n = mi * 16 + qd * 4;
            u16 v[4];
            for (int r = 0; r < 4; r++) v[r] = f2bf(acc[mi][ni][r]);
            *(uint2*)&L.Ct[f * 68 + n] = *(uint2*)v;
        }
    }
    __syncthreads();
    if (t < 64) { sig[m0 + t] = L.s1[t]; sjg[m0 + t] = L.s2[t]; }
    {
        int fr = t;
        size_t base = (size_t)b * 524288 + (size_t)fr * 2048 + n0;
        #pragma unroll
        for (int s = 0; s < 8; s++) {
            uint4 v = *(uint4*)&L.Ct[fr * 68 + s * 8];
            *(uint4*)(whbt + base + s * 8) = v;
        }
    }
}

// ---------------- K3n: per-batch shift + factored-exp tables -------------
__global__ __launch_bounds__(512) void k3n(const float* __restrict__ sig, const float* __restrict__ sjg,
                                           float* __restrict__ u1g, float* __restrict__ u2g,
                                           u32* __restrict__ vpackg, u16* __restrict__ sjbfg) {
    int b = blockIdx.x;
    int t = threadIdx.x;
    const float* sjb = sjg + (size_t)b * 2048;
    float mx = -3.4e38f;
    #pragma unroll
    for (int p = 0; p < 4; p++) mx = fmaxf(mx, sjb[t + p * 512]);
    for (int d = 32; d; d >>= 1) mx = fmaxf(mx, __shfl_xor(mx, d));
    __shared__ float wmax[8];
    int wid = t >> 6, lane = t & 63;
    if (lane == 0) wmax[wid] = mx;
    __syncthreads();
    float Mb = fmaxf(fmaxf(fmaxf(wmax[0], wmax[1]), fmaxf(wmax[2], wmax[3])),
                     fmaxf(fmaxf(wmax[4], wmax[5]), fmaxf(wmax[6], wmax[7])));
    #pragma unroll
    for (int p = 0; p < 4; p++) {
        int j = t + p * 512;
        float sjv = sjb[j];
        float vj  = __expf(sjv - Mb);
        float v2j = __expf(0.2f * (sjv - Mb));
        vpackg[b * 2048 + j] = (u32)f2bf(vj) | ((u32)f2bf(v2j) << 16);
        sjbfg[b * 2048 + j]  = f2bf(sjv);
        float siv = sig[b * 2048 + j];
        float x = siv + Mb;
        float K = fmaxf(x, 0.2f * x);
        u1g[b * 2048 + j] = __expf(x - K);
        u2g[b * 2048 + j] = __expf(0.2f * x - K);
    }
}

// ---------------- K4: XCD-pinned batch + reg-B + P-gen + MFMA + ELU ------
// 256 blocks x 512 thr. Block reads HW_REG_XCC_ID and claims a 64-row tile
// of batch b == its own XCD via atomic counters -> whbt[b] is L2-resident
// on that XCD only (work-stealing fallback keeps correctness regardless of
// the XCD mapping). 8 waves, each owns a 32-f slice: B read once per block.
struct __align__(16) K4LDS {
    u32   vpack[2048];                 // 8192 B
    u16   sjb[2048];                   // 4096 B
    u64   mw[64 * 33];                 // 16896 B
    float u1[64], u2[64], nsi[64], inv[64];
    float lred[512];
    u16   Pt[2][4096];                 // 2 x 8192 B, [octet][row][8]
    int   claim[2];
};
__global__ __launch_bounds__(512, 1) void k4(const float* __restrict__ sig,
                                             const float* __restrict__ u1g, const float* __restrict__ u2g,
                                             const u32* __restrict__ vpackg, const u16* __restrict__ sjbfg,
                                             const u64* __restrict__ mb64, const u16* __restrict__ whbt,
                                             void* __restrict__ out, const void* __restrict__ hdet,
                                             int* __restrict__ cnt) {
    __shared__ K4LDS L;
    int f32 = detect_f32((const u32*)hdet);
    int t = threadIdx.x;
    if (t == 0) {
        // HW_REG_XCC_ID = id 20, offset 0, size 32 -> imm = 20 | (31<<11)
        int xcd = __builtin_amdgcn_s_getreg(63508) & 7;
        int bsel = 0, tile = 0;
        #pragma unroll
        for (int k = 0; k < 8; k++) {
            int bb = (xcd + k) & 7;
            int tt = atomicAdd(&cnt[bb], 1);
            if (tt < 32) { bsel = bb; tile = tt; break; }
        }
        L.claim[0] = bsel; L.claim[1] = tile;
    }
    __syncthreads();
    int b  = L.claim[0];
    int i0 = L.claim[1] * 64;
    int wid = t >> 6, lane = t & 63, ln = lane & 15, qd = lane >> 4;
    const u16* wb = whbt + (size_t)b * 524288 + (size_t)wid * 32 * 2048;
    float lacc = 0.f;

    // B frags for chunk cc: wave owns f-rows wid*32..+31 (no duplication)
    bf16x8 br[2][4];
    #define LOAD_B(cc, bb) do {                                             \
        int j0_ = (cc) * 64;                                                \
        _Pragma("unroll")                                                   \
        for (int ni = 0; ni < 2; ni++)                                      \
            _Pragma("unroll")                                               \
            for (int ks = 0; ks < 2; ks++)                                  \
                br[bb][ni * 2 + ks] = *(const bf16x8*)(wb +                 \
                    (size_t)(ni * 16 + ln) * 2048 + j0_ + ks * 32 + qd * 8);\
    } while (0)

    // Factored P-gen: thread -> row lane, j-octet wid; accumulates lacc.
    #define PGEN(cc, bb) do {                                               \
        int r_ = lane, o_ = wid;                                            \
        int jb_ = (cc) * 64 + o_ * 8;                                       \
        uint4 pkA_ = *(const uint4*)&L.vpack[jb_];                          \
        uint4 pkB_ = *(const uint4*)&L.vpack[jb_ + 4];                      \
        uint4 sj4_ = *(const uint4*)&L.sjb[jb_];                            \
        u32 mb_ = (u32)(L.mw[r_ * 33 + (cc)] >> (o_ * 8)) & 0xffu;          \
        float u1_ = L.u1[r_], u2_ = L.u2[r_], nsi_ = L.nsi[r_];             \
        u32 pr_[4];                                                         \
        _Pragma("unroll")                                                   \
        for (int pk = 0; pk < 4; pk++) {                                    \
            u32 vw0_ = (pk == 0) ? pkA_.x : (pk == 1) ? pkA_.z              \
                     : (pk == 2) ? pkB_.x : pkB_.z;                         \
            u32 vw1_ = (pk == 0) ? pkA_.y : (pk == 1) ? pkA_.w              \
                     : (pk == 2) ? pkB_.y : pkB_.w;                         \
            u32 sw_ = (pk == 0) ? sj4_.x : (pk == 1) ? sj4_.y               \
                     : (pk == 2) ? sj4_.z : sj4_.w;                         \
            float sj0_ = __uint_as_float(sw_ << 16);                        \
            float sj1_ = __uint_as_float(sw_ & 0xffff0000u);                \
            float p0_, p1_;                                                 \
            {                                                               \
                bool pos = sj0_ > nsi_;                                     \
                float vv = __uint_as_float(pos ? (vw0_ << 16)               \
                                               : ((vw0_ >> 16) << 16));     \
                p0_ = (pos ? u1_ : u2_) * vv;                               \
                p0_ = ((mb_ >> (2 * pk)) & 1u) ? p0_ : 0.f;                 \
            }                                                               \
            {                                                               \
                bool pos = sj1_ > nsi_;                                     \
                float vv = __uint_as_float(pos ? (vw1_ << 16)               \
                                               : ((vw1_ >> 16) << 16));     \
                p1_ = (pos ? u1_ : u2_) * vv;                               \
                p1_ = ((mb_ >> (2 * pk + 1)) & 1u) ? p1_ : 0.f;             \
            }                                                               \
            lacc += p0_ + p1_;                                              \
            pr_[pk] = __builtin_amdgcn_perm(__float_as_uint(p1_),           \
                                            __float_as_uint(p0_),           \
                                            0x07060302u);                   \
        }                                                                   \
        *(uint4*)&L.Pt[bb][t * 8] = *(uint4*)pr_;                           \
    } while (0)

    LOAD_B(0, 0);
    // stage tables
    for (int p = 0; p < 4; p++) { int idx = t + p * 512; L.vpack[idx] = vpackg[b * 2048 + idx]; }
    for (int p = 0; p < 2; p++) { int idx = t + p * 512;
        ((u32*)L.sjb)[idx] = ((const u32*)(sjbfg + (size_t)b * 2048))[idx]; }
    for (int p = 0; p < 4; p++) {
        int idx = t + p * 512;                          // 2048 u64 words
        int r = idx >> 5, c = idx & 31;
        L.mw[r * 33 + c] = mb64[(size_t)(i0 + r) * 32 + c];
    }
    if (t < 64) {
        int row = b * 2048 + i0 + t;
        L.u1[t] = u1g[row]; L.u2[t] = u2g[row]; L.nsi[t] = -sig[row];
    }
    __syncthreads();
    PGEN(0, 0);

    f32x4 acc[4][2];
    for (int mi = 0; mi < 4; mi++)
        for (int ni = 0; ni < 2; ni++)
            acc[mi][ni] = (f32x4){0.f, 0.f, 0.f, 0.f};

    // one barrier per K-chunk; B(c+1) regs + PGEN(c+1) overlap MFMA(c)
    #define STEP(c, cur, nxt) do {                                          \
        __syncthreads();                                                    \
        if ((c) < 31) { LOAD_B((c) + 1, nxt); PGEN((c) + 1, nxt); }         \
        _Pragma("unroll")                                                   \
        for (int ks = 0; ks < 2; ks++) {                                    \
            bf16x8 af[4];                                                   \
            _Pragma("unroll")                                               \
            for (int mi = 0; mi < 4; mi++)                                  \
                af[mi] = *(const bf16x8*)&L.Pt[cur][((ks * 4 + qd) * 64 +   \
                                                     mi * 16 + ln) * 8];    \
            _Pragma("unroll")                                               \
            for (int mi = 0; mi < 4; mi++)                                  \
                _Pragma("unroll")                                           \
                for (int ni = 0; ni < 2; ni++)                              \
                    acc[mi][ni] = MFMA_BF16(af[mi], br[cur][ni * 2 + ks],   \
                                            acc[mi][ni]);                   \
        }                                                                   \
    } while (0)

    for (int cc = 0; cc < 16; cc++) {
        STEP(2 * cc,     0, 1);
        STEP(2 * cc + 1, 1, 0);
    }

    // reduce row sums l_i: 8 partials per row (t = octet*64 + row)
    __syncthreads();
    L.lred[t] = lacc;
    __syncthreads();
    if (t < 64) {
        float s = 0.f;
        #pragma unroll
        for (int q = 0; q < 8; q++) s += L.lred[q * 64 + t];
        L.inv[t] = 1.0f / s;
    }
    __syncthreads();

    // epilogue: h_prime = acc * inv_l, ELU, store
    for (int mi = 0; mi < 4; mi++) {
        for (int ni = 0; ni < 2; ni++) {
            int fg = wid * 32 + ni * 16 + ln;
            for (int reg = 0; reg < 4; reg++) {
                int rl = mi * 16 + qd * 4 + reg;
                float hp = acc[mi][ni][reg] * L.inv[rl];
                float y = hp > 0.f ? hp : (__expf(hp) - 1.f);
                size_t idx = (size_t)(b * 2048 + i0 + rl) * 256 + fg;
                if (f32) ((float*)out)[idx] = y;
                else     ((u16*)out)[idx]   = f2bf(y);
            }
        }
    }
    #undef LOAD_B
    #undef PGEN
    #undef STEP
}

// ---------------- launch --------------------------------------------------
extern "C" void kernel_launch(void* const* d_in, const int* in_sizes, int n_in,
                              void* d_out, int out_size, void* d_ws, size_t ws_size,
                              hipStream_t stream) {
    const void* h   = d_in[0];              // (8,2048,256) fp32 (detected) or bf16
    const int*  adj = (const int*)d_in[1];  // int32 (2048,2048)
    const void* W   = d_in[2];              // (256,256)
    const void* a   = d_in[3];              // (512,1)

    char* ws = (char*)d_ws;
    u16*   WT    = (u16*)  (ws + 0);        // 131072
    float* si    = (float*)(ws + 131072);   // 65536
    float* sj    = (float*)(ws + 196608);   // 65536
    float* u1    = (float*)(ws + 262144);   // 65536
    float* u2    = (float*)(ws + 327680);   // 65536
    u32*   vpack = (u32*)  (ws + 458752);   // 65536
    u16*   sjbf  = (u16*)  (ws + 524288);   // 32768
    u64*   mb64  = (u64*)  (ws + 557056);   // 524288
    u16*   whbt  = (u16*)  (ws + 1081344);  // 8388608 (end 9469952)
    float* Wa1   = (float*)(ws + 9469952);  // 1024
    float* Wa2   = (float*)(ws + 9470976);  // 1024
    int*   cnt   = (int*)  (ws + 9472000);  // 32

    hipMemsetAsync(cnt, 0, 32, stream);
    k0 <<<dim3(256),  dim3(256), 0, stream>>>(W, a, WT, Wa1, Wa2, (const u32*)h);
    k1m<<<dim3(4096), dim3(256), 0, stream>>>(adj, mb64);
    k2 <<<dim3(256),  dim3(256), 0, stream>>>(h, WT, Wa1, Wa2, whbt, si, sj);
    k3n<<<dim3(8),    dim3(512), 0, stream>>>(si, sj, u1, u2, vpack, sjbf);
    k4 <<<dim3(256),  dim3(512), 0, stream>>>(si, u1, u2, vpack, sjbf, mb64, whbt, d_out, h, cnt);
}